// Round 9
// baseline (2248.474 us; speedup 1.0000x reference)
//
#include <hip/hip_runtime.h>
#include <cstdio>

// MoE top-2 FFN: B=4,S=2048,D=1024 -> T=8192 tokens; E=8, H=4096, K_TOP=2.
// Round 9: (1) ILP-rich LDS-free weight transpose (8 loads/thread, coalesced
// u16x8 stores) replacing the latency-bound r8 version; (2) GEMM back to
// BK=32/16KB/(256,6) (r2's best) + 4x4 supertile grid for L2 + pad-tile skip;
// (3) everything else (prep fusion, atomic GEMM2 epilogue) kept from r8.

#define T_TOK 8192
#define DIM   1024
#define NEXP  8
#define HID   4096
#define MAXR  18432  // 16384 rows + 8 experts * up-to-255 pad, rounded to 256

typedef float          f32x4   __attribute__((ext_vector_type(4)));
typedef short          bf16x8  __attribute__((ext_vector_type(8)));
typedef unsigned short u16x8   __attribute__((ext_vector_type(8)));
typedef unsigned short u16x4   __attribute__((ext_vector_type(4)));

static __device__ __forceinline__ unsigned short f2bf(float f) {
  unsigned int u = __builtin_bit_cast(unsigned int, f);
  u = (u + 0x7FFFu + ((u >> 16) & 1u)) >> 16;   // round-nearest-even (finite inputs)
  return (unsigned short)u;
}

// async global->LDS, 16B per lane; LDS dest = wave-uniform base + lane*16
static __device__ __forceinline__ void gl16(const void* g, void* l) {
  __builtin_amdgcn_global_load_lds(
      (const __attribute__((address_space(1))) unsigned int*)g,
      (__attribute__((address_space(3))) unsigned int*)l,
      16, 0, 0);
}

// ---------------- transpose + fp32->bf16, LDS-free, ILP=8 --------------------
// W[e][R][C] fp32 -> WT[e][C][R] bf16.  Block = 64 rows x 128 cols, 4 waves
// (wave w: cols w*32..w*32+31).  Lane: r8=(lane&7)*8 rows, cg=lane>>3 col-grp.
// Loads: 8x float4 (row-strided).  Stores: 4x u16x8; lanes sharing cg span
// rows r0..r0+63 -> 128B-contiguous output runs per column.
static __device__ __forceinline__ void transpose_body(const float* __restrict__ W,
                                                      unsigned short* __restrict__ WT,
                                                      int R, int C, int bx, int by, int e) {
  int lane = threadIdx.x & 63, w = threadIdx.x >> 6;
  int r0 = by * 64, c0 = bx * 128 + w * 32;
  int r8 = (lane & 7) * 8, cg = lane >> 3;
  const float* src = W + (size_t)e * R * C + (size_t)(r0 + r8) * C + c0 + cg * 4;
  float4 v[8];
#pragma unroll
  for (int j = 0; j < 8; ++j) v[j] = *(const float4*)(src + (size_t)j * C);
  unsigned short* dst = WT + (size_t)e * R * C + (size_t)(c0 + cg * 4) * R + r0 + r8;
#pragma unroll
  for (int s = 0; s < 4; ++s) {
    u16x8 o;
#pragma unroll
    for (int j = 0; j < 8; ++j) {
      float f = s == 0 ? v[j].x : s == 1 ? v[j].y : s == 2 ? v[j].z : v[j].w;
      o[j] = f2bf(f);
    }
    *(u16x8*)(dst + (size_t)s * R) = o;
  }
}

static __device__ __forceinline__ void router_body(int blk, const float* __restrict__ x,
                                                   const float* __restrict__ Wr,
                                                   const float* __restrict__ br,
                                                   int* __restrict__ meta,
                                                   int2* __restrict__ top_i,
                                                   float2* __restrict__ top_w) {
  int lane = threadIdx.x & 63;
  int wid  = threadIdx.x >> 6;
  int t = blk * 4 + wid;
  const float* xp = x + (size_t)t * DIM + lane * 16;
  float acc[NEXP];
#pragma unroll
  for (int e = 0; e < NEXP; ++e) acc[e] = 0.f;
#pragma unroll
  for (int j = 0; j < 16; j += 4) {
    float4 xv = *(const float4*)(xp + j);
    const float* wp = Wr + (size_t)(lane * 16 + j) * NEXP;
#pragma unroll
    for (int jj = 0; jj < 4; ++jj) {
      float xs = jj == 0 ? xv.x : jj == 1 ? xv.y : jj == 2 ? xv.z : xv.w;
      float4 w0 = *(const float4*)(wp + jj * NEXP);
      float4 w1 = *(const float4*)(wp + jj * NEXP + 4);
      acc[0] += xs * w0.x; acc[1] += xs * w0.y; acc[2] += xs * w0.z; acc[3] += xs * w0.w;
      acc[4] += xs * w1.x; acc[5] += xs * w1.y; acc[6] += xs * w1.z; acc[7] += xs * w1.w;
    }
  }
#pragma unroll
  for (int off = 32; off > 0; off >>= 1) {
#pragma unroll
    for (int e = 0; e < NEXP; ++e) acc[e] += __shfl_xor(acc[e], off);
  }
  if (lane == 0) {
    float l[NEXP];
#pragma unroll
    for (int e = 0; e < NEXP; ++e) l[e] = acc[e] + br[e];
    int e1 = 0;
#pragma unroll
    for (int e = 1; e < NEXP; ++e) if (l[e] > l[e1]) e1 = e;      // ties -> lower idx
    int e2 = (e1 == 0) ? 1 : 0;
#pragma unroll
    for (int e = 0; e < NEXP; ++e) if (e != e1 && l[e] > l[e2]) e2 = e;
    float g  = expf(l[e2] - l[e1]);              // softmax over top-2 == renorm of full softmax
    float w1 = 1.f / (1.f + g);
    top_i[t] = make_int2(e1, e2);
    top_w[t] = make_float2(w1, 1.f - w1);
    atomicAdd(&meta[e1], 1);
    atomicAdd(&meta[e2], 1);
  }
}

// ---- fused prep: [0,4096) W1 transpose, [4096,8192) W2 transpose,
//      [8192,10240) router, [10240,10312) fill pad-row arrays ----------------
__global__ __launch_bounds__(256) void prep_k(const float* __restrict__ W1,
                                              const float* __restrict__ W2,
                                              unsigned short* __restrict__ W1bT,
                                              unsigned short* __restrict__ W2bT,
                                              const float* __restrict__ x,
                                              const float* __restrict__ Wr,
                                              const float* __restrict__ br,
                                              int* __restrict__ meta,
                                              int2* __restrict__ top_i,
                                              float2* __restrict__ top_w,
                                              int* __restrict__ tok_of_row,
                                              float* __restrict__ wt_of_row) {
  int id = blockIdx.x;
  if (id < 4096) {                               // W1[e][D][H] -> [e][H][D]
    int rem = id & 511;                          // 16 by x 32 bx per expert
    transpose_body(W1, W1bT, DIM, HID, rem & 31, rem >> 5, id >> 9);
  } else if (id < 8192) {                        // W2[e][H][D] -> [e][D][H]
    int id2 = id - 4096;
    int rem = id2 & 511;                         // 64 by x 8 bx per expert
    transpose_body(W2, W2bT, HID, DIM, rem & 7, rem >> 3, id2 >> 9);
  } else if (id < 10240) {
    router_body(id - 8192, x, Wr, br, meta, top_i, top_w);
  } else {
    int i = (id - 10240) * 256 + threadIdx.x;    // 72*256 == MAXR exactly
    if (i < MAXR) { tok_of_row[i] = 0; wt_of_row[i] = 0.f; }
  }
}

// -------- prefix: padded (x256) offsets ------------------------------------
__global__ void prefix_k(int* __restrict__ meta) {
  if (threadIdx.x == 0) {
    int s = 0;
#pragma unroll
    for (int e = 0; e < NEXP; ++e) {
      meta[16 + e] = s;                          // poff[e]
      s += (meta[e] + 255) & ~255;
    }
    meta[24] = s;                                // poff[8]
    meta[25] = s;                                // total_padded (<= MAXR always)
  }
}

// ---------------- scatter: token -> packed expert row ------------------------
__global__ __launch_bounds__(256) void scatter_k(const int2* __restrict__ top_i,
                                                 const float2* __restrict__ top_w,
                                                 int* __restrict__ meta,
                                                 int* __restrict__ row_of,
                                                 int* __restrict__ tok_of_row,
                                                 float* __restrict__ wt_of_row) {
  int t = blockIdx.x * 256 + threadIdx.x;
  int2  ei = top_i[t];
  float2 w = top_w[t];
  int p = atomicAdd(&meta[8 + ei.x], 1);
  int r = meta[16 + ei.x] + p;
  tok_of_row[r] = t; wt_of_row[r] = w.x; row_of[t * 2] = r;
  p = atomicAdd(&meta[8 + ei.y], 1);
  r = meta[16 + ei.y] + p;
  tok_of_row[r] = t; wt_of_row[r] = w.y; row_of[t * 2 + 1] = r;
}

// ---------------- gather: xg[r][:] = bf16(x[tok[r]][:]) ----------------------
__global__ __launch_bounds__(256) void gather_k(const float* __restrict__ x,
                                                const int* __restrict__ tok_of_row,
                                                const int* __restrict__ meta,
                                                unsigned short* __restrict__ xg) {
  int r = blockIdx.x;
  if (r >= meta[25]) return;
  int t = tok_of_row[r];
  int c = threadIdx.x * 4;
  float4 v = *(const float4*)(x + (size_t)t * DIM + c);
  u16x4 o;
  o[0] = f2bf(v.x); o[1] = f2bf(v.y); o[2] = f2bf(v.z); o[3] = f2bf(v.w);
  *(u16x4*)(xg + (size_t)r * DIM + c) = o;
}

// ---------------- grouped GEMM: r2 loop (BK=32) + swizzle + supertile --------
// A: [M][KTOT] bf16 packed rows.  Bt: [E][NTOT][KTOT] bf16 (pre-transposed).
// 128x128 tile, BK=32, 4 waves (2x2), 16KB LDS (A shorts [0,4096), B [4096,8192)).
// LDS region = [128 rows][4 slots x 8 shorts]; slot XOR-swizzled by (row>>1)&3
// (r5-validated).  Grid: XCD-chunked, 4x4 supertiles (16 consecutive ids =
// 4 row-tiles x 4 n-tiles), row-sub fastest.  Pad-only tiles skipped.
// Per K-tile: sync; 4x gl16; sync; 8x ds_read_b128; 16x mfma_16x16x32_bf16.
// EPI 0: h = bf16(gelu(acc+b1))   EPI 1: atomicAdd out[tok] += (acc+b2)*wt

template <int KTOT, int NTOT, int EPI>
__global__ __launch_bounds__(256, 6) void gemmv9_k(const unsigned short* __restrict__ A,
                                                   const unsigned short* __restrict__ Bt,
                                                   const float* __restrict__ bias,
                                                   const int* __restrict__ meta,
                                                   const float* __restrict__ wt_of_row,
                                                   const int* __restrict__ tok_of_row,
                                                   void* __restrict__ Cout) {
  constexpr int NN  = NTOT / 128;                // 32 or 8
  constexpr int NXB = MAXR / 128;                // 144 row tiles
  constexpr int NWG = NXB * NN;                  // 4608 or 1152, both % 8 == 0
  constexpr int NSR = NXB / 4;                   // 36 row supertiles
  constexpr int NKT = KTOT / 32;
  __shared__ __align__(16) unsigned short lds[8192];   // 16 KiB

  // XCD chunking, then 4x4 supertile decode (row-sub fastest)
  int id = ((int)blockIdx.x & 7) * (NWG / 8) + ((int)blockIdx.x >> 3);
  int sid = id >> 4, sub = id & 15;
  int row0 = ((sid % NSR) * 4 + (sub & 3)) * 128;
  int n0   = ((sid / NSR) * 4 + (sub >> 2)) * 128;
  if (row0 >= meta[25]) return;                  // beyond padded total (block-uniform)
  int e = 0;
  while (meta[17 + e] <= row0) ++e;              // tiles never straddle experts
  if (row0 - meta[16 + e] >= meta[e]) return;    // all-pad tile: skip (wt==0 gates EPI1;
                                                 // EPI0's unwritten hbuf rows are finite
                                                 // garbage multiplied by wt==0 in GEMM2)
  const unsigned short* Bp = Bt + (size_t)e * NTOT * KTOT;

  int tid = threadIdx.x;
  int lane = tid & 63, wid = tid >> 6;
  int wm = wid >> 1, wn = wid & 1;               // 2x2 waves, each owns 64x64 of C

  // staging (T2 write side): granules tid (rows 0..63) and tid+256 (rows 64..127);
  // row = tid>>2, slot' = tid&3; source col-slot s = (tid&3) ^ ((tid>>3)&3)
  int s = (tid & 3) ^ ((tid >> 3) & 3);
  const unsigned short* pA0 = A + (size_t)(row0 + (tid >> 2)) * KTOT + s * 8;
  const unsigned short* pA1 = pA0 + (size_t)64 * KTOT;
  const unsigned short* pB0 = Bp + (size_t)(n0 + (tid >> 2)) * KTOT + s * 8;
  const unsigned short* pB1 = pB0 + (size_t)64 * KTOT;

  // fragment reads (T2 read side): row = w*64 + i*16 + am; slot = g ^ ((row>>1)&3)
  int am = lane & 15;
  int sF = ((lane >> 4) ^ ((lane >> 1) & 3)) * 8;
  int aoff = (wm * 64 + am) * 32 + sF;           // + i*512 per fragment
  int boff = 4096 + (wn * 64 + am) * 32 + sF;    // + j*512 per fragment

  f32x4 acc[4][4];
#pragma unroll
  for (int i = 0; i < 4; ++i)
#pragma unroll
    for (int j = 0; j < 4; ++j) acc[i][j] = (f32x4){0.f, 0.f, 0.f, 0.f};

  for (int kt = 0; kt < NKT; ++kt) {
    __syncthreads();                             // prev compute done before overwrite
    gl16(pA0 + kt * 32, lds + tid * 8);
    gl16(pA1 + kt * 32, lds + 2048 + tid * 8);
    gl16(pB0 + kt * 32, lds + 4096 + tid * 8);
    gl16(pB1 + kt * 32, lds + 6144 + tid * 8);
    __syncthreads();                             // compiler drains vmcnt before barrier
    bf16x8 af[4], bv[4];
#pragma unroll
    for (int i = 0; i < 4; ++i)
      af[i] = *(const bf16x8*)(lds + aoff + i * 512);
#pragma unroll
    for (int j = 0; j < 4; ++j)
      bv[j] = *(const bf16x8*)(lds + boff + j * 512);
#pragma unroll
    for (int i = 0; i < 4; ++i)
#pragma unroll
      for (int j = 0; j < 4; ++j)
        acc[i][j] = __builtin_amdgcn_mfma_f32_16x16x32_bf16(af[i], bv[j], acc[i][j], 0, 0, 0);
  }

  // epilogue.  C/D: col n = lane&15, row m = (lane>>4)*4 + reg  (validated)
  int rbase = row0 + wm * 64 + ((lane >> 4) << 2);
  int nbase = n0 + wn * 64 + am;
  if constexpr (EPI == 0) {
    unsigned short* Hp = (unsigned short*)Cout;
    const float* bp = bias + (size_t)e * NTOT;
#pragma unroll
    for (int i = 0; i < 4; ++i)
#pragma unroll
      for (int j = 0; j < 4; ++j) {
        int n = nbase + j * 16;
        float bv = bp[n];
#pragma unroll
        for (int g = 0; g < 4; ++g) {
          int m = rbase + i * 16 + g;
          float v = acc[i][j][g] + bv;
          v = 0.5f * v * (1.f + erff(v * 0.70710678118654752f));   // exact gelu
          Hp[(size_t)m * NTOT + n] = f2bf(v);
        }
      }
  } else {
    float* Op = (float*)Cout;
    const float* bp = bias + (size_t)e * NTOT;
#pragma unroll
    for (int i = 0; i < 4; ++i)
#pragma unroll
      for (int g = 0; g < 4; ++g) {
        int m = rbase + i * 16 + g;
        float wt = wt_of_row[m];
        if (wt != 0.f) {                         // pad rows excluded (wt exactly 0)
          float* orow = Op + (size_t)tok_of_row[m] * DIM;
#pragma unroll
          for (int j = 0; j < 4; ++j) {
            int n = nbase + j * 16;
            atomicAdd(orow + n, (acc[i][j][g] + bp[n]) * wt);
          }
        }
      }
  }
}

extern "C" void kernel_launch(void* const* d_in, const int* in_sizes, int n_in,
                              void* d_out, int out_size, void* d_ws, size_t ws_size,
                              hipStream_t stream) {
  const float* x  = (const float*)d_in[0];
  const float* Wr = (const float*)d_in[1];
  const float* br = (const float*)d_in[2];
  const float* W1 = (const float*)d_in[3];
  const float* b1 = (const float*)d_in[4];
  const float* W2 = (const float*)d_in[5];
  const float* b2 = (const float*)d_in[6];
  float* out = (float*)d_out;

  char* base = (char*)d_ws;
  size_t off = 0;
  auto carve = [&](size_t bytes) -> void* {
    void* r = base + off;
    off = (off + bytes + 255) & ~(size_t)255;
    return r;
  };
  int*            meta       = (int*)carve(26 * 4);
  int2*           top_i      = (int2*)carve((size_t)T_TOK * 8);
  float2*         top_w      = (float2*)carve((size_t)T_TOK * 8);
  int*            row_of     = (int*)carve((size_t)T_TOK * 2 * 4);
  int*            tok_of_row = (int*)carve((size_t)MAXR * 4);
  float*          wt_of_row  = (float*)carve((size_t)MAXR * 4);
  unsigned short* xg         = (unsigned short*)carve((size_t)MAXR * DIM * 2);
  unsigned short* W1bT       = (unsigned short*)carve((size_t)NEXP * DIM * HID * 2);
  unsigned short* W2bT       = (unsigned short*)carve((size_t)NEXP * DIM * HID * 2);
  unsigned short* hbuf       = (unsigned short*)carve((size_t)MAXR * HID * 2);
  if (off > ws_size) {
    fprintf(stderr, "kernel_launch: ws_size too small: need %zu have %zu\n", off, ws_size);
    return;
  }

  hipMemsetAsync(meta, 0, 26 * 4, stream);
  hipMemsetAsync(out, 0, (size_t)out_size * 4, stream);   // GEMM2 atomicAdds into out
  hipLaunchKernelGGL(prep_k, dim3(10312), dim3(256), 0, stream,
                     W1, W2, W1bT, W2bT, x, Wr, br, meta, top_i, top_w,
                     tok_of_row, wt_of_row);
  hipLaunchKernelGGL(prefix_k, dim3(1), dim3(64), 0, stream, meta);
  hipLaunchKernelGGL(scatter_k, dim3(T_TOK / 256), dim3(256), 0, stream,
                     top_i, top_w, meta, row_of, tok_of_row, wt_of_row);
  hipLaunchKernelGGL(gather_k, dim3(MAXR), dim3(256), 0, stream, x, tok_of_row, meta, xg);
  hipLaunchKernelGGL((gemmv9_k<DIM, HID, 0>), dim3((MAXR / 128) * (HID / 128)), dim3(256), 0,
                     stream, xg, W1bT, b1, meta, wt_of_row, tok_of_row, (void*)hbuf);
  hipLaunchKernelGGL((gemmv9_k<HID, DIM, 1>), dim3((MAXR / 128) * (DIM / 128)), dim3(256), 0,
                     stream, hbuf, W2bT, b2, meta, wt_of_row, tok_of_row, (void*)out);
}

// Round 10
// 866.586 us; speedup vs baseline: 2.5946x; 2.5946x over previous
//
#include <hip/hip_runtime.h>
#include <cstdio>

// MoE top-2 FFN: B=4,S=2048,D=1024 -> T=8192 tokens; E=8, H=4096, K_TOP=2.
// Round 10: r9 with the REAL regression fixed: __launch_bounds__(256,6) had
// capped VGPRs at 40 -> accumulator spilled to scratch -> 2.3GB of global
// write traffic (same root cause as r7, previously mis-attributed to NT
// stores). Now (256,4) like r8 (56 VGPR, no spill). Keeps r9's ILP-8
// LDS-free transpose, 4x4 supertile grid, pad-tile skip, T2 swizzle.

#define T_TOK 8192
#define DIM   1024
#define NEXP  8
#define HID   4096
#define MAXR  18432  // 16384 rows + 8 experts * up-to-255 pad, rounded to 256

typedef float          f32x4   __attribute__((ext_vector_type(4)));
typedef short          bf16x8  __attribute__((ext_vector_type(8)));
typedef unsigned short u16x8   __attribute__((ext_vector_type(8)));
typedef unsigned short u16x4   __attribute__((ext_vector_type(4)));

static __device__ __forceinline__ unsigned short f2bf(float f) {
  unsigned int u = __builtin_bit_cast(unsigned int, f);
  u = (u + 0x7FFFu + ((u >> 16) & 1u)) >> 16;   // round-nearest-even (finite inputs)
  return (unsigned short)u;
}

// async global->LDS, 16B per lane; LDS dest = wave-uniform base + lane*16
static __device__ __forceinline__ void gl16(const void* g, void* l) {
  __builtin_amdgcn_global_load_lds(
      (const __attribute__((address_space(1))) unsigned int*)g,
      (__attribute__((address_space(3))) unsigned int*)l,
      16, 0, 0);
}

// ---------------- transpose + fp32->bf16, LDS-free, ILP=8 --------------------
// W[e][R][C] fp32 -> WT[e][C][R] bf16.  Block = 64 rows x 128 cols, 4 waves
// (wave w: cols w*32..w*32+31).  Lane: r8=(lane&7)*8 rows, cg=lane>>3 col-grp.
// Loads: 8x float4 (row-strided).  Stores: 4x u16x8; lanes sharing cg span
// rows r0..r0+63 -> 128B-contiguous output runs per column.
static __device__ __forceinline__ void transpose_body(const float* __restrict__ W,
                                                      unsigned short* __restrict__ WT,
                                                      int R, int C, int bx, int by, int e) {
  int lane = threadIdx.x & 63, w = threadIdx.x >> 6;
  int r0 = by * 64, c0 = bx * 128 + w * 32;
  int r8 = (lane & 7) * 8, cg = lane >> 3;
  const float* src = W + (size_t)e * R * C + (size_t)(r0 + r8) * C + c0 + cg * 4;
  float4 v[8];
#pragma unroll
  for (int j = 0; j < 8; ++j) v[j] = *(const float4*)(src + (size_t)j * C);
  unsigned short* dst = WT + (size_t)e * R * C + (size_t)(c0 + cg * 4) * R + r0 + r8;
#pragma unroll
  for (int s = 0; s < 4; ++s) {
    u16x8 o;
#pragma unroll
    for (int j = 0; j < 8; ++j) {
      float f = s == 0 ? v[j].x : s == 1 ? v[j].y : s == 2 ? v[j].z : v[j].w;
      o[j] = f2bf(f);
    }
    *(u16x8*)(dst + (size_t)s * R) = o;
  }
}

static __device__ __forceinline__ void router_body(int blk, const float* __restrict__ x,
                                                   const float* __restrict__ Wr,
                                                   const float* __restrict__ br,
                                                   int* __restrict__ meta,
                                                   int2* __restrict__ top_i,
                                                   float2* __restrict__ top_w) {
  int lane = threadIdx.x & 63;
  int wid  = threadIdx.x >> 6;
  int t = blk * 4 + wid;
  const float* xp = x + (size_t)t * DIM + lane * 16;
  float acc[NEXP];
#pragma unroll
  for (int e = 0; e < NEXP; ++e) acc[e] = 0.f;
#pragma unroll
  for (int j = 0; j < 16; j += 4) {
    float4 xv = *(const float4*)(xp + j);
    const float* wp = Wr + (size_t)(lane * 16 + j) * NEXP;
#pragma unroll
    for (int jj = 0; jj < 4; ++jj) {
      float xs = jj == 0 ? xv.x : jj == 1 ? xv.y : jj == 2 ? xv.z : xv.w;
      float4 w0 = *(const float4*)(wp + jj * NEXP);
      float4 w1 = *(const float4*)(wp + jj * NEXP + 4);
      acc[0] += xs * w0.x; acc[1] += xs * w0.y; acc[2] += xs * w0.z; acc[3] += xs * w0.w;
      acc[4] += xs * w1.x; acc[5] += xs * w1.y; acc[6] += xs * w1.z; acc[7] += xs * w1.w;
    }
  }
#pragma unroll
  for (int off = 32; off > 0; off >>= 1) {
#pragma unroll
    for (int e = 0; e < NEXP; ++e) acc[e] += __shfl_xor(acc[e], off);
  }
  if (lane == 0) {
    float l[NEXP];
#pragma unroll
    for (int e = 0; e < NEXP; ++e) l[e] = acc[e] + br[e];
    int e1 = 0;
#pragma unroll
    for (int e = 1; e < NEXP; ++e) if (l[e] > l[e1]) e1 = e;      // ties -> lower idx
    int e2 = (e1 == 0) ? 1 : 0;
#pragma unroll
    for (int e = 0; e < NEXP; ++e) if (e != e1 && l[e] > l[e2]) e2 = e;
    float g  = expf(l[e2] - l[e1]);              // softmax over top-2 == renorm of full softmax
    float w1 = 1.f / (1.f + g);
    top_i[t] = make_int2(e1, e2);
    top_w[t] = make_float2(w1, 1.f - w1);
    atomicAdd(&meta[e1], 1);
    atomicAdd(&meta[e2], 1);
  }
}

// ---- fused prep: [0,4096) W1 transpose, [4096,8192) W2 transpose,
//      [8192,10240) router, [10240,10312) fill pad-row arrays ----------------
__global__ __launch_bounds__(256) void prep_k(const float* __restrict__ W1,
                                              const float* __restrict__ W2,
                                              unsigned short* __restrict__ W1bT,
                                              unsigned short* __restrict__ W2bT,
                                              const float* __restrict__ x,
                                              const float* __restrict__ Wr,
                                              const float* __restrict__ br,
                                              int* __restrict__ meta,
                                              int2* __restrict__ top_i,
                                              float2* __restrict__ top_w,
                                              int* __restrict__ tok_of_row,
                                              float* __restrict__ wt_of_row) {
  int id = blockIdx.x;
  if (id < 4096) {                               // W1[e][D][H] -> [e][H][D]
    int rem = id & 511;                          // 16 by x 32 bx per expert
    transpose_body(W1, W1bT, DIM, HID, rem & 31, rem >> 5, id >> 9);
  } else if (id < 8192) {                        // W2[e][H][D] -> [e][D][H]
    int id2 = id - 4096;
    int rem = id2 & 511;                         // 64 by x 8 bx per expert
    transpose_body(W2, W2bT, HID, DIM, rem & 7, rem >> 3, id2 >> 9);
  } else if (id < 10240) {
    router_body(id - 8192, x, Wr, br, meta, top_i, top_w);
  } else {
    int i = (id - 10240) * 256 + threadIdx.x;    // 72*256 == MAXR exactly
    if (i < MAXR) { tok_of_row[i] = 0; wt_of_row[i] = 0.f; }
  }
}

// -------- prefix: padded (x256) offsets ------------------------------------
__global__ void prefix_k(int* __restrict__ meta) {
  if (threadIdx.x == 0) {
    int s = 0;
#pragma unroll
    for (int e = 0; e < NEXP; ++e) {
      meta[16 + e] = s;                          // poff[e]
      s += (meta[e] + 255) & ~255;
    }
    meta[24] = s;                                // poff[8]
    meta[25] = s;                                // total_padded (<= MAXR always)
  }
}

// ---------------- scatter: token -> packed expert row ------------------------
__global__ __launch_bounds__(256) void scatter_k(const int2* __restrict__ top_i,
                                                 const float2* __restrict__ top_w,
                                                 int* __restrict__ meta,
                                                 int* __restrict__ row_of,
                                                 int* __restrict__ tok_of_row,
                                                 float* __restrict__ wt_of_row) {
  int t = blockIdx.x * 256 + threadIdx.x;
  int2  ei = top_i[t];
  float2 w = top_w[t];
  int p = atomicAdd(&meta[8 + ei.x], 1);
  int r = meta[16 + ei.x] + p;
  tok_of_row[r] = t; wt_of_row[r] = w.x; row_of[t * 2] = r;
  p = atomicAdd(&meta[8 + ei.y], 1);
  r = meta[16 + ei.y] + p;
  tok_of_row[r] = t; wt_of_row[r] = w.y; row_of[t * 2 + 1] = r;
}

// ---------------- gather: xg[r][:] = bf16(x[tok[r]][:]) ----------------------
__global__ __launch_bounds__(256) void gather_k(const float* __restrict__ x,
                                                const int* __restrict__ tok_of_row,
                                                const int* __restrict__ meta,
                                                unsigned short* __restrict__ xg) {
  int r = blockIdx.x;
  if (r >= meta[25]) return;
  int t = tok_of_row[r];
  int c = threadIdx.x * 4;
  float4 v = *(const float4*)(x + (size_t)t * DIM + c);
  u16x4 o;
  o[0] = f2bf(v.x); o[1] = f2bf(v.y); o[2] = f2bf(v.z); o[3] = f2bf(v.w);
  *(u16x4*)(xg + (size_t)r * DIM + c) = o;
}

// ---------------- grouped GEMM: r2 loop (BK=32) + swizzle + supertile --------
// A: [M][KTOT] bf16 packed rows.  Bt: [E][NTOT][KTOT] bf16 (pre-transposed).
// 128x128 tile, BK=32, 4 waves (2x2), 16KB LDS (A shorts [0,4096), B [4096,8192)).
// LDS region = [128 rows][4 slots x 8 shorts]; slot XOR-swizzled by (row>>1)&3
// (r5-validated).  Grid: XCD-chunked, 4x4 supertiles (16 consecutive ids =
// 4 row-tiles x 4 n-tiles), row-sub fastest.  Pad-only tiles skipped.
// Per K-tile: sync; 4x gl16; sync; 8x ds_read_b128; 16x mfma_16x16x32_bf16.
// EPI 0: h = bf16(gelu(acc+b1))   EPI 1: atomicAdd out[tok] += (acc+b2)*wt
// NOTE: min-waves must stay <=4 — (256,6) caps VGPR at 40 and spills acc (r7/r9).

template <int KTOT, int NTOT, int EPI>
__global__ __launch_bounds__(256, 4) void gemmv10_k(const unsigned short* __restrict__ A,
                                                    const unsigned short* __restrict__ Bt,
                                                    const float* __restrict__ bias,
                                                    const int* __restrict__ meta,
                                                    const float* __restrict__ wt_of_row,
                                                    const int* __restrict__ tok_of_row,
                                                    void* __restrict__ Cout) {
  constexpr int NN  = NTOT / 128;                // 32 or 8
  constexpr int NXB = MAXR / 128;                // 144 row tiles
  constexpr int NWG = NXB * NN;                  // 4608 or 1152, both % 8 == 0
  constexpr int NSR = NXB / 4;                   // 36 row supertiles
  constexpr int NKT = KTOT / 32;
  __shared__ __align__(16) unsigned short lds[8192];   // 16 KiB

  // XCD chunking, then 4x4 supertile decode (row-sub fastest)
  int id = ((int)blockIdx.x & 7) * (NWG / 8) + ((int)blockIdx.x >> 3);
  int sid = id >> 4, sub = id & 15;
  int row0 = ((sid % NSR) * 4 + (sub & 3)) * 128;
  int n0   = ((sid / NSR) * 4 + (sub >> 2)) * 128;
  if (row0 >= meta[25]) return;                  // beyond padded total (block-uniform)
  int e = 0;
  while (meta[17 + e] <= row0) ++e;              // tiles never straddle experts
  if (row0 - meta[16 + e] >= meta[e]) return;    // all-pad tile: skip (wt==0 gates EPI1;
                                                 // EPI0's unwritten hbuf rows are finite
                                                 // garbage multiplied by wt==0 in GEMM2)
  const unsigned short* Bp = Bt + (size_t)e * NTOT * KTOT;

  int tid = threadIdx.x;
  int lane = tid & 63, wid = tid >> 6;
  int wm = wid >> 1, wn = wid & 1;               // 2x2 waves, each owns 64x64 of C

  // staging (T2 write side): granules tid (rows 0..63) and tid+256 (rows 64..127);
  // row = tid>>2, slot' = tid&3; source col-slot s = (tid&3) ^ ((tid>>3)&3)
  int s = (tid & 3) ^ ((tid >> 3) & 3);
  const unsigned short* pA0 = A + (size_t)(row0 + (tid >> 2)) * KTOT + s * 8;
  const unsigned short* pA1 = pA0 + (size_t)64 * KTOT;
  const unsigned short* pB0 = Bp + (size_t)(n0 + (tid >> 2)) * KTOT + s * 8;
  const unsigned short* pB1 = pB0 + (size_t)64 * KTOT;

  // fragment reads (T2 read side): row = w*64 + i*16 + am; slot = g ^ ((row>>1)&3)
  int am = lane & 15;
  int sF = ((lane >> 4) ^ ((lane >> 1) & 3)) * 8;
  int aoff = (wm * 64 + am) * 32 + sF;           // + i*512 per fragment
  int boff = 4096 + (wn * 64 + am) * 32 + sF;    // + j*512 per fragment

  f32x4 acc[4][4];
#pragma unroll
  for (int i = 0; i < 4; ++i)
#pragma unroll
    for (int j = 0; j < 4; ++j) acc[i][j] = (f32x4){0.f, 0.f, 0.f, 0.f};

  for (int kt = 0; kt < NKT; ++kt) {
    __syncthreads();                             // prev compute done before overwrite
    gl16(pA0 + kt * 32, lds + tid * 8);
    gl16(pA1 + kt * 32, lds + 2048 + tid * 8);
    gl16(pB0 + kt * 32, lds + 4096 + tid * 8);
    gl16(pB1 + kt * 32, lds + 6144 + tid * 8);
    __syncthreads();                             // compiler drains vmcnt before barrier
    bf16x8 af[4], bv[4];
#pragma unroll
    for (int i = 0; i < 4; ++i)
      af[i] = *(const bf16x8*)(lds + aoff + i * 512);
#pragma unroll
    for (int j = 0; j < 4; ++j)
      bv[j] = *(const bf16x8*)(lds + boff + j * 512);
#pragma unroll
    for (int i = 0; i < 4; ++i)
#pragma unroll
      for (int j = 0; j < 4; ++j)
        acc[i][j] = __builtin_amdgcn_mfma_f32_16x16x32_bf16(af[i], bv[j], acc[i][j], 0, 0, 0);
  }

  // epilogue.  C/D: col n = lane&15, row m = (lane>>4)*4 + reg  (validated)
  int rbase = row0 + wm * 64 + ((lane >> 4) << 2);
  int nbase = n0 + wn * 64 + am;
  if constexpr (EPI == 0) {
    unsigned short* Hp = (unsigned short*)Cout;
    const float* bp = bias + (size_t)e * NTOT;
#pragma unroll
    for (int i = 0; i < 4; ++i)
#pragma unroll
      for (int j = 0; j < 4; ++j) {
        int n = nbase + j * 16;
        float bv = bp[n];
#pragma unroll
        for (int g = 0; g < 4; ++g) {
          int m = rbase + i * 16 + g;
          float v = acc[i][j][g] + bv;
          v = 0.5f * v * (1.f + erff(v * 0.70710678118654752f));   // exact gelu
          Hp[(size_t)m * NTOT + n] = f2bf(v);
        }
      }
  } else {
    float* Op = (float*)Cout;
    const float* bp = bias + (size_t)e * NTOT;
#pragma unroll
    for (int i = 0; i < 4; ++i)
#pragma unroll
      for (int g = 0; g < 4; ++g) {
        int m = rbase + i * 16 + g;
        float wt = wt_of_row[m];
        if (wt != 0.f) {                         // pad rows excluded (wt exactly 0)
          float* orow = Op + (size_t)tok_of_row[m] * DIM;
#pragma unroll
          for (int j = 0; j < 4; ++j) {
            int n = nbase + j * 16;
            atomicAdd(orow + n, (acc[i][j][g] + bp[n]) * wt);
          }
        }
      }
  }
}

extern "C" void kernel_launch(void* const* d_in, const int* in_sizes, int n_in,
                              void* d_out, int out_size, void* d_ws, size_t ws_size,
                              hipStream_t stream) {
  const float* x  = (const float*)d_in[0];
  const float* Wr = (const float*)d_in[1];
  const float* br = (const float*)d_in[2];
  const float* W1 = (const float*)d_in[3];
  const float* b1 = (const float*)d_in[4];
  const float* W2 = (const float*)d_in[5];
  const float* b2 = (const float*)d_in[6];
  float* out = (float*)d_out;

  char* base = (char*)d_ws;
  size_t off = 0;
  auto carve = [&](size_t bytes) -> void* {
    void* r = base + off;
    off = (off + bytes + 255) & ~(size_t)255;
    return r;
  };
  int*            meta       = (int*)carve(26 * 4);
  int2*           top_i      = (int2*)carve((size_t)T_TOK * 8);
  float2*         top_w      = (float2*)carve((size_t)T_TOK * 8);
  int*            row_of     = (int*)carve((size_t)T_TOK * 2 * 4);
  int*            tok_of_row = (int*)carve((size_t)MAXR * 4);
  float*          wt_of_row  = (float*)carve((size_t)MAXR * 4);
  unsigned short* xg         = (unsigned short*)carve((size_t)MAXR * DIM * 2);
  unsigned short* W1bT       = (unsigned short*)carve((size_t)NEXP * DIM * HID * 2);
  unsigned short* W2bT       = (unsigned short*)carve((size_t)NEXP * DIM * HID * 2);
  unsigned short* hbuf       = (unsigned short*)carve((size_t)MAXR * HID * 2);
  if (off > ws_size) {
    fprintf(stderr, "kernel_launch: ws_size too small: need %zu have %zu\n", off, ws_size);
    return;
  }

  hipMemsetAsync(meta, 0, 26 * 4, stream);
  hipMemsetAsync(out, 0, (size_t)out_size * 4, stream);   // GEMM2 atomicAdds into out
  hipLaunchKernelGGL(prep_k, dim3(10312), dim3(256), 0, stream,
                     W1, W2, W1bT, W2bT, x, Wr, br, meta, top_i, top_w,
                     tok_of_row, wt_of_row);
  hipLaunchKernelGGL(prefix_k, dim3(1), dim3(64), 0, stream, meta);
  hipLaunchKernelGGL(scatter_k, dim3(T_TOK / 256), dim3(256), 0, stream,
                     top_i, top_w, meta, row_of, tok_of_row, wt_of_row);
  hipLaunchKernelGGL(gather_k, dim3(MAXR), dim3(256), 0, stream, x, tok_of_row, meta, xg);
  hipLaunchKernelGGL((gemmv10_k<DIM, HID, 0>), dim3((MAXR / 128) * (HID / 128)), dim3(256), 0,
                     stream, xg, W1bT, b1, meta, wt_of_row, tok_of_row, (void*)hbuf);
  hipLaunchKernelGGL((gemmv10_k<HID, DIM, 1>), dim3((MAXR / 128) * (DIM / 128)), dim3(256), 0,
                     stream, hbuf, W2bT, b2, meta, wt_of_row, tok_of_row, (void*)out);
}